// Round 9
// baseline (176.241 us; speedup 1.0000x reference)
//
#include <hip/hip_runtime.h>

// Problem constants (match reference)
#define BB 4096
#define DD 16
#define MM 4
#define RR 2048
#define CC 10
#define TB 2            // batch rows per block -> grid 2048 = 8 blocks/CU
#define RPT (RR / 256)  // rules per thread = 8
#define REPS 5          // MEASUREMENT round: surface anfis_main's counter row.
                        // NEXT ROUND: REPS=1 final config.

typedef __attribute__((ext_vector_type(4))) float f32x4;
typedef __attribute__((ext_vector_type(2))) float f32x2;

// ---------------- prep kernel (unchanged from R8) ----------------
__global__ __launch_bounds__(256) void prep_kernel(
    const float* __restrict__ cons, const int* __restrict__ rules,
    float* __restrict__ wsum4a, float* __restrict__ wsum4b,
    float* __restrict__ wsum2, unsigned int* __restrict__ codes)
{
    int gid = blockIdx.x * 256 + threadIdx.x;
    if (gid < RR * CC) {
        int r = gid / CC, c = gid - r * CC;
        const float* cr = cons + (size_t)r * (DD + 1) * CC + c;
        float s = 0.0f;
#pragma unroll
        for (int j = 0; j < DD + 1; ++j) s += cr[j * CC];
        if (c < 4)      wsum4a[r * 4 + c] = s;
        else if (c < 8) wsum4b[r * 4 + (c - 4)] = s;
        else            wsum2[r * 2 + (c - 8)] = s;
    }
    if (gid < RR) {
        const int* rrp = rules + gid * DD;
        unsigned int code = 0;
#pragma unroll
        for (int g = 0; g < 4; ++g) {
            unsigned int byt = 0;
#pragma unroll
            for (int k = 0; k < 4; ++k)
                byt |= (((unsigned int)rrp[g * 4 + k]) & 3u) << (2 * k);
            code |= byt << (8 * g);
        }
        codes[gid] = code;
    }
}

// ---------------- main kernel ----------------
// R8's TB=2 structure (two-pass, unroll-1 rule loops, f32x2 tables ->
// ds_read_b64 gathers, 8 blocks/CU) with phases 1b..5 wrapped in a REPS
// loop for direct dispatch measurement (R4-style instrumentation).
__global__ __launch_bounds__(256, 8) void anfis_main(
    const float* __restrict__ x, const float* __restrict__ centers,
    const float* __restrict__ widths, const f32x4* __restrict__ wsum4a,
    const f32x4* __restrict__ wsum4b, const f32x2* __restrict__ wsum2,
    const unsigned int* __restrict__ codes,
    float* __restrict__ out, float* __restrict__ norm_fs, float* __restrict__ x_ext)
{
    // Q2 (8 KB) aliased with RED (5.4 KB): last Q2 read (phase-4 gathers) is
    // barrier-separated from RED writes (phase 5); tables are rebuilt each rep.
    __shared__ __align__(16) char pool[4 * 256 * sizeof(f32x2)];
    f32x2 (*Q2)[256] = (f32x2 (*)[256])pool;   // [g][e] -> 2 rows
    float (*RED)[68] = (float (*)[68])pool;    // [20][64+pad]

    __shared__ float MF[TB][64];     // [row][d*4+m]
    __shared__ f32x2 PAIR2[8][16];   // [p][i0+4*i1] -> 2 rows
    __shared__ float xs[TB][DD];
    __shared__ float sx[TB];
    __shared__ float wpart[4][TB];
    __shared__ float invl[TB];
    __shared__ float oscale[TB];
    __shared__ float part2[TB * CC][4];

    const int tid = threadIdx.x;
    const int b0 = blockIdx.x * TB;
    const int lane = tid & 63;
    const int wv = tid >> 6;

    // ---- phase 1a: load x rows, emit x_ext (once) ----
    if (tid < TB * (DD + 1)) {
        int row = tid / (DD + 1), col = tid % (DD + 1);
        float v = (col < DD) ? x[(b0 + row) * DD + col] : 1.0f;
        if (col < DD) xs[row][col] = v;
        x_ext[(b0 + row) * (DD + 1) + col] = v;
    }
    __syncthreads();
    if (tid < TB) {
        float s = 1.0f;
#pragma unroll
        for (int d = 0; d < DD; ++d) s += xs[tid][d];
        sx[tid] = s;
    }

#pragma unroll 1
    for (int rep = 0; rep < REPS; ++rep) {
        __syncthreads();  // prior-rep part2/RED reads done before pool rewrite

        // ---- phase 1b: membership values (2 rows x 64) ----
        if (tid < TB * 64) {
            int row = tid >> 6, dm = tid & 63, d = dm >> 2, m = dm & 3;
            float c = centers[d * MM + m];
            float w = widths[d * MM + m];
            float z = xs[row][d] - c;
            MF[row][dm] = expf(-(z * z) / (2.0f * w * w));
        }
        __syncthreads();

        // ---- phase 1c: pair tables, row-interleaved (f32x2) ----
        if (tid < 8 * 16) {
            int p = tid >> 4, e = tid & 15;
            int i0 = e & 3, i1 = e >> 2;
            f32x2 v;
            v.x = MF[0][(2 * p) * 4 + i0] * MF[0][(2 * p + 1) * 4 + i1];
            v.y = MF[1][(2 * p) * 4 + i0] * MF[1][(2 * p + 1) * 4 + i1];
            PAIR2[p][e] = v;
        }
        __syncthreads();

        // ---- phase 1d: quad tables, row-interleaved (f32x2) ----
#pragma unroll
        for (int i = tid; i < 4 * 256; i += 256) {
            int g = i >> 8, e = i & 255;
            Q2[g][e] = PAIR2[2 * g][e & 15] * PAIR2[2 * g + 1][e >> 4];
        }
        __syncthreads();

        // ---- phase 2: firing-strength row sums (gather pass 1) ----
        float ssum0 = 0.0f, ssum1 = 0.0f;
#pragma unroll 1
        for (int j = 0; j < RPT; ++j) {
            unsigned int code = codes[tid + 256 * j];
            f32x2 q0 = Q2[0][code & 255u];
            f32x2 q1 = Q2[1][(code >> 8) & 255u];
            f32x2 q2 = Q2[2][(code >> 16) & 255u];
            f32x2 q3 = Q2[3][code >> 24];
            f32x2 p = (q0 * q1) * (q2 * q3);
            ssum0 += p.x;
            ssum1 += p.y;
        }

        // ---- phase 3: per-row fs total across block ----
        {
            float s0 = ssum0, s1 = ssum1;
#pragma unroll
            for (int off = 32; off > 0; off >>= 1) {
                s0 += __shfl_xor(s0, off, 64);
                s1 += __shfl_xor(s1, off, 64);
            }
            if (lane == 0) { wpart[wv][0] = s0; wpart[wv][1] = s1; }
        }
        __syncthreads();
        if (tid < TB) {
            float t = wpart[0][tid] + wpart[1][tid] + wpart[2][tid] + wpart[3][tid];
            float inv = 1.0f / (t + 1e-9f);
            invl[tid] = inv;
            oscale[tid] = sx[tid] * inv;
        }
        __syncthreads();

        const float inv0 = invl[0], inv1 = invl[1];

        // ---- phase 4: re-gather, write norm_fs, accumulate fs*Wsum ----
        float acc[TB][CC];
#pragma unroll
        for (int row = 0; row < TB; ++row)
#pragma unroll
            for (int c = 0; c < CC; ++c) acc[row][c] = 0.0f;

#pragma unroll 1
        for (int j = 0; j < RPT; ++j) {
            int r = tid + 256 * j;
            unsigned int code = codes[r];
            f32x2 q0 = Q2[0][code & 255u];
            f32x2 q1 = Q2[1][(code >> 8) & 255u];
            f32x2 q2 = Q2[2][(code >> 16) & 255u];
            f32x2 q3 = Q2[3][code >> 24];
            f32x2 p = (q0 * q1) * (q2 * q3);

            norm_fs[(size_t)(b0 + 0) * RR + r] = p.x * inv0;
            norm_fs[(size_t)(b0 + 1) * RR + r] = p.y * inv1;

            const f32x4 wa = wsum4a[r];
            const f32x4 wb = wsum4b[r];
            const f32x2 wcp = wsum2[r];
            const float wc[CC] = {wa.x, wa.y, wa.z, wa.w, wb.x,
                                  wb.y, wb.z, wb.w, wcp.x, wcp.y};
#pragma unroll
            for (int c = 0; c < CC; ++c) {
                acc[0][c] = fmaf(p.x, wc[c], acc[0][c]);
                acc[1][c] = fmaf(p.y, wc[c], acc[1][c]);
            }
        }
        __syncthreads();  // Q2 reads drained -> RED aliasing safe

        // ---- phase 5: reduce acc across block ----
#pragma unroll
        for (int row = 0; row < TB; ++row) {
#pragma unroll
            for (int c = 0; c < CC; ++c) {
                float s = acc[row][c];
                s += __shfl_xor(s, 1, 64);
                s += __shfl_xor(s, 2, 64);
                if ((lane & 3) == 0) RED[row * CC + c][wv * 16 + (lane >> 2)] = s;
            }
        }
        __syncthreads();
        if (tid < 80) {
            int v = tid % 20, ch = tid / 20;   // 4 chunks of 16 columns
            float s = 0.0f;
            int base = ch * 16;
#pragma unroll
            for (int i = 0; i < 16; ++i) s += RED[v][base + i];
            part2[v][ch] = s;
        }
        __syncthreads();
        if (tid < TB * CC) {
            float val = part2[tid][0] + part2[tid][1] + part2[tid][2] + part2[tid][3];
            int row = tid / CC, c = tid % CC;
            out[(b0 + row) * CC + c] = oscale[row] * val;
        }
    }
}

// ---------------- launch ----------------
extern "C" void kernel_launch(void* const* d_in, const int* in_sizes, int n_in,
                              void* d_out, int out_size, void* d_ws, size_t ws_size,
                              hipStream_t stream) {
    const float* x       = (const float*)d_in[0];
    const float* centers = (const float*)d_in[1];
    const float* widths  = (const float*)d_in[2];
    const float* cons    = (const float*)d_in[3];
    const int*   rules   = (const int*)d_in[4];

    float* out_p     = (float*)d_out;                       // (B, C)
    float* norm_fs_p = out_p + (size_t)BB * CC;             // (B, R)
    float* x_ext_p   = norm_fs_p + (size_t)BB * RR;         // (B, D+1)

    // workspace layout: wsum4a (32KB) | wsum4b (32KB) | wsum2 (16KB) | codes (8KB)
    float* wsum4a = (float*)d_ws;
    float* wsum4b = wsum4a + (size_t)RR * 4;
    float* wsum2  = wsum4b + (size_t)RR * 4;
    unsigned int* codes = (unsigned int*)(wsum2 + (size_t)RR * 2);

    prep_kernel<<<(RR * CC + 255) / 256, 256, 0, stream>>>(cons, rules, wsum4a,
                                                           wsum4b, wsum2, codes);
    anfis_main<<<BB / TB, 256, 0, stream>>>(x, centers, widths,
                                            (const f32x4*)wsum4a,
                                            (const f32x4*)wsum4b,
                                            (const f32x2*)wsum2, codes,
                                            out_p, norm_fs_p, x_ext_p);
}

// Round 10
// 86.738 us; speedup vs baseline: 2.0319x; 2.0319x over previous
//
#include <hip/hip_runtime.h>

// Problem constants (match reference)
#define BB 4096
#define DD 16
#define MM 4
#define RR 2048
#define CC 10
#define TB 4            // batch rows per block -> grid 1024
#define RPT (RR / 256)  // rules per thread = 8

typedef __attribute__((ext_vector_type(4))) float f32x4;
typedef __attribute__((ext_vector_type(2))) float f32x2;
typedef __attribute__((ext_vector_type(4))) unsigned short u16x4;

// bf16 pack/unpack (RNE); fs >= 0, never NaN. Range = f32 (no underflow,
// unlike fp16 -- raw fs can be ~1e-30). Only norm_fs sees the 0.4% rounding.
__device__ __forceinline__ unsigned short f2bf(float x) {
    union { float f; unsigned u; } v; v.f = x;
    unsigned b = v.u + 0x7FFFu + ((v.u >> 16) & 1u);
    return (unsigned short)(b >> 16);
}
__device__ __forceinline__ float bf2f(unsigned short h) {
    union { unsigned u; float f; } v; v.u = ((unsigned)h) << 16;
    return v.f;
}

// ---------------- prep kernel (unchanged from R8) ----------------
__global__ __launch_bounds__(256) void prep_kernel(
    const float* __restrict__ cons, const int* __restrict__ rules,
    float* __restrict__ wsum4a, float* __restrict__ wsum4b,
    float* __restrict__ wsum2, unsigned int* __restrict__ codes)
{
    int gid = blockIdx.x * 256 + threadIdx.x;
    if (gid < RR * CC) {
        int r = gid / CC, c = gid - r * CC;
        const float* cr = cons + (size_t)r * (DD + 1) * CC + c;
        float s = 0.0f;
#pragma unroll
        for (int j = 0; j < DD + 1; ++j) s += cr[j * CC];
        if (c < 4)      wsum4a[r * 4 + c] = s;
        else if (c < 8) wsum4b[r * 4 + (c - 4)] = s;
        else            wsum2[r * 2 + (c - 8)] = s;
    }
    if (gid < RR) {
        const int* rrp = rules + gid * DD;
        unsigned int code = 0;
#pragma unroll
        for (int g = 0; g < 4; ++g) {
            unsigned int byt = 0;
#pragma unroll
            for (int k = 0; k < 4; ++k)
                byt |= (((unsigned int)rrp[g * 4 + k]) & 3u) << (2 * k);
            code |= byt << (8 * g);
        }
        codes[gid] = code;
    }
}

// ---------------- main kernel ----------------
// TB=4, SINGLE gather pass: pass 1 gathers p (f32x4 over rows), accumulates
// svec + raw-fs acc FMAs, and stores fs as bf16 in FS[2048] (u16x4, 8B
// granule -> conflict-free stride-1 LDS). Pass 2 = ds_read_b64 + unpack +
// *inv + coalesced store (no gathers, no decode). LDS 36KB -> 4 blocks/CU.
__global__ __launch_bounds__(256, 4) void anfis_main(
    const float* __restrict__ x, const float* __restrict__ centers,
    const float* __restrict__ widths, const f32x4* __restrict__ wsum4a,
    const f32x4* __restrict__ wsum4b, const f32x2* __restrict__ wsum2,
    const unsigned int* __restrict__ codes,
    float* __restrict__ out, float* __restrict__ norm_fs, float* __restrict__ x_ext)
{
    // QUAD4 (16 KB) aliased with RED (10.9 KB): last QUAD4 read is in pass 1
    // (phase 2); the phase-3 barriers separate it from RED writes (phase 5).
    __shared__ __align__(16) char pool[4 * 256 * sizeof(f32x4)];
    f32x4 (*QUAD4)[256] = (f32x4 (*)[256])pool;  // [g][e] -> 4 rows
    float (*RED)[68]    = (float (*)[68])pool;   // [40][64+pad]

    __shared__ u16x4 FS[RR];         // 16 KB: fs[r] as bf16 x 4 rows
    __shared__ float MF[TB][64];     // [row][d*4+m]
    __shared__ f32x4 PAIR4[8][16];   // [p][i0+4*i1] -> 4 rows
    __shared__ float xs[TB][DD];
    __shared__ float sx[TB];
    __shared__ float wpart[4][TB];
    __shared__ float invl[TB];
    __shared__ float oscale[TB];
    __shared__ float part2[TB * CC][4];

    const int tid = threadIdx.x;
    const int b0 = blockIdx.x * TB;
    const int lane = tid & 63;
    const int wv = tid >> 6;

    // ---- phase 1a: load x rows, emit x_ext ----
    if (tid < TB * (DD + 1)) {
        int row = tid / (DD + 1), col = tid % (DD + 1);
        float v = (col < DD) ? x[(b0 + row) * DD + col] : 1.0f;
        if (col < DD) xs[row][col] = v;
        x_ext[(b0 + row) * (DD + 1) + col] = v;
    }
    __syncthreads();
    if (tid < TB) {
        float s = 1.0f;
#pragma unroll
        for (int d = 0; d < DD; ++d) s += xs[tid][d];
        sx[tid] = s;
    }

    // ---- phase 1b: membership values (4 rows x 64, one per thread) ----
    {
        int row = tid >> 6, dm = tid & 63, d = dm >> 2, m = dm & 3;
        float c = centers[d * MM + m];
        float w = widths[d * MM + m];
        float z = xs[row][d] - c;
        MF[row][dm] = expf(-(z * z) / (2.0f * w * w));
    }
    __syncthreads();

    // ---- phase 1c: pair tables, row-interleaved ----
    if (tid < 8 * 16) {
        int p = tid >> 4, e = tid & 15;
        int i0 = e & 3, i1 = e >> 2;
        f32x4 v;
#pragma unroll
        for (int row = 0; row < TB; ++row)
            v[row] = MF[row][(2 * p) * 4 + i0] * MF[row][(2 * p + 1) * 4 + i1];
        PAIR4[p][e] = v;
    }
    __syncthreads();

    // ---- phase 1d: quad tables, row-interleaved ----
#pragma unroll
    for (int i = tid; i < 4 * 256; i += 256) {
        int g = i >> 8, e = i & 255;
        QUAD4[g][e] = PAIR4[2 * g][e & 15] * PAIR4[2 * g + 1][e >> 4];
    }
    __syncthreads();

    // ---- phase 2 (pass 1): gather p once; svec, raw-fs acc, FS store ----
    float acc[TB][CC];
#pragma unroll
    for (int row = 0; row < TB; ++row)
#pragma unroll
        for (int c = 0; c < CC; ++c) acc[row][c] = 0.0f;

    f32x4 svec = {0.0f, 0.0f, 0.0f, 0.0f};

#pragma unroll 1
    for (int j = 0; j < RPT; ++j) {
        int r = tid + 256 * j;
        unsigned int code = codes[r];
        f32x4 q0 = QUAD4[0][code & 255u];
        f32x4 q1 = QUAD4[1][(code >> 8) & 255u];
        f32x4 q2 = QUAD4[2][(code >> 16) & 255u];
        f32x4 q3 = QUAD4[3][code >> 24];
        f32x4 p = (q0 * q1) * (q2 * q3);
        svec += p;

        u16x4 fh;
        fh.x = f2bf(p[0]); fh.y = f2bf(p[1]);
        fh.z = f2bf(p[2]); fh.w = f2bf(p[3]);
        FS[r] = fh;  // ds_write_b64, conflict-free stride-1

        const f32x4 wa = wsum4a[r];
        const f32x4 wb = wsum4b[r];
        const f32x2 wcp = wsum2[r];
        const float wc[CC] = {wa.x, wa.y, wa.z, wa.w, wb.x,
                              wb.y, wb.z, wb.w, wcp.x, wcp.y};
#pragma unroll
        for (int row = 0; row < TB; ++row)
#pragma unroll
            for (int c = 0; c < CC; ++c)
                acc[row][c] = fmaf(p[row], wc[c], acc[row][c]);
    }

    // ---- phase 3: per-row fs total across block ----
#pragma unroll
    for (int row = 0; row < TB; ++row) {
        float s = svec[row];
#pragma unroll
        for (int off = 32; off > 0; off >>= 1) s += __shfl_xor(s, off, 64);
        if (lane == 0) wpart[wv][row] = s;
    }
    __syncthreads();
    if (tid < TB) {
        float t = wpart[0][tid] + wpart[1][tid] + wpart[2][tid] + wpart[3][tid];
        float inv = 1.0f / (t + 1e-9f);
        invl[tid] = inv;
        oscale[tid] = sx[tid] * inv;
    }
    __syncthreads();

    const float inv0 = invl[0], inv1 = invl[1], inv2 = invl[2], inv3 = invl[3];

    // ---- phase 4 (pass 2): FS read + normalize + coalesced store ----
#pragma unroll 1
    for (int j = 0; j < RPT; ++j) {
        int r = tid + 256 * j;
        u16x4 fh = FS[r];  // ds_read_b64, conflict-free stride-1
        norm_fs[(size_t)(b0 + 0) * RR + r] = bf2f(fh.x) * inv0;
        norm_fs[(size_t)(b0 + 1) * RR + r] = bf2f(fh.y) * inv1;
        norm_fs[(size_t)(b0 + 2) * RR + r] = bf2f(fh.z) * inv2;
        norm_fs[(size_t)(b0 + 3) * RR + r] = bf2f(fh.w) * inv3;
    }

    // ---- phase 5: reduce acc across block (RED aliases dead QUAD4) ----
#pragma unroll
    for (int row = 0; row < TB; ++row) {
#pragma unroll
        for (int c = 0; c < CC; ++c) {
            float s = acc[row][c];
            s += __shfl_xor(s, 1, 64);
            s += __shfl_xor(s, 2, 64);
            if ((lane & 3) == 0) RED[row * CC + c][wv * 16 + (lane >> 2)] = s;
        }
    }
    __syncthreads();
    if (tid < 160) {
        int v = tid % 40, ch = tid / 40;   // 4 chunks of 16 columns
        float s = 0.0f;
        int base = ch * 16;
#pragma unroll
        for (int i = 0; i < 16; ++i) s += RED[v][base + i];
        part2[v][ch] = s;
    }
    __syncthreads();
    if (tid < TB * CC) {
        float val = part2[tid][0] + part2[tid][1] + part2[tid][2] + part2[tid][3];
        int row = tid / CC, c = tid % CC;
        out[(b0 + row) * CC + c] = oscale[row] * val;
    }
}

// ---------------- launch ----------------
extern "C" void kernel_launch(void* const* d_in, const int* in_sizes, int n_in,
                              void* d_out, int out_size, void* d_ws, size_t ws_size,
                              hipStream_t stream) {
    const float* x       = (const float*)d_in[0];
    const float* centers = (const float*)d_in[1];
    const float* widths  = (const float*)d_in[2];
    const float* cons    = (const float*)d_in[3];
    const int*   rules   = (const int*)d_in[4];

    float* out_p     = (float*)d_out;                       // (B, C)
    float* norm_fs_p = out_p + (size_t)BB * CC;             // (B, R)
    float* x_ext_p   = norm_fs_p + (size_t)BB * RR;         // (B, D+1)

    // workspace: wsum4a (32KB) | wsum4b (32KB) | wsum2 (16KB) | codes (8KB)
    float* wsum4a = (float*)d_ws;
    float* wsum4b = wsum4a + (size_t)RR * 4;
    float* wsum2  = wsum4b + (size_t)RR * 4;
    unsigned int* codes = (unsigned int*)(wsum2 + (size_t)RR * 2);

    prep_kernel<<<(RR * CC + 255) / 256, 256, 0, stream>>>(cons, rules, wsum4a,
                                                           wsum4b, wsum2, codes);
    anfis_main<<<BB / TB, 256, 0, stream>>>(x, centers, widths,
                                            (const f32x4*)wsum4a,
                                            (const f32x4*)wsum4b,
                                            (const f32x2*)wsum2, codes,
                                            out_p, norm_fs_p, x_ext_p);
}